// Round 13
// baseline (764.401 us; speedup 1.0000x reference)
//
#include <hip/hip_runtime.h>
#include <hip/hip_fp16.h>

// Kuramoto phase dynamics + coherence softmax. B*S=1024 rows, V=50257, 10 steps.
// Two-pass trajectory scheme (validated r11/r12, absmax 2.38e-7 = 1 ulp),
// packed f32 math (v_pk_fma_f32), re-tiled for 512-THREAD BLOCKS:
//   The allocator pins VGPRs to a 2-blocks/CU budget (observed 64 @1024t,
//   84 @768t == 512-reg file / (2*block_waves/4)). At 512t that budget is
//   128 VGPRs -- enough for 30 register pair-stripes + 21 accumulators with
//   no spill -- and 2x78.5 KB LDS fits 160 KB, so occupancy doubles to
//   16 waves/CU (4/SIMD).
// Layout per row: 49 pair-stripes of 1024 elems (pairs (2tid,2tid+1)):
//   stripes 0..29 in registers (rst[30], f16 s|c pair packed in uint2),
//   stripes 30..48 in LDS (st[19][512], thread-private columns),
//   tail = 81 elems (50176..50256) scalar in regs for tid<81.
// Pass A: p0 = nz+0.1*lg; (s,c)=sincos; stash f16 state; rotate 10 steps via
//   float4 tbl (ts0,ts1,td0,td1 = sin(.1w), cos(.1w)-1); accumulate S_t,C_t
//   (t=0..9) + Sum(p0). One 21-value block reduce (barrier #1).
//   dSt/dCt/cM/sM -> SGPR via readfirstlane; mean uses ws Sum(omega)
//   (sum_i eps_i == 0 identically in the lagged scheme).
// Pass B: re-rotate from state; eps = sum_t(s_t*dCt[t] - c_t*dSt[t]);
//   1st-order eps rotation; coh = c*cM + s*sM; e = exp(coh) stashed over
//   state. esum reduce (barrier #2). Pass C: out = e*inv, packed stores.
// LDS loops pinned to unroll 1: per-element 10-step chain is issue-bound
// (~80 instr vs ~80 cyc dep latency); extra in-flight pairs only add spill
// risk (r12 lesson).

#define V_DIM   50257
#define NROWS   1024
#define NT      512
#define NSR     30                // register pair-stripes
#define NSL     19                // LDS pair-stripes
#define NSTOT   (NSR + NSL)       // 49 stripes x 1024 elems = 50176
#define STRIDE  (2 * NT)          // 1024
#define TAIL_B  (NSTOT * STRIDE)  // 50176
#define TAILN   (V_DIM - TAIL_B)  // 81
#define NSTEP   10
#define INV2PI  0.15915494309189535f
#define DTC     (0.1f * (0.1f / (float)V_DIM))

typedef float v2f __attribute__((ext_vector_type(2)));

__device__ __forceinline__ float fsin(float r) { return __builtin_amdgcn_sinf(r); }
__device__ __forceinline__ float fcos(float r) { return __builtin_amdgcn_cosf(r); }
__device__ __forceinline__ float rfl(float x) {
    return __builtin_bit_cast(float, __builtin_amdgcn_readfirstlane(__builtin_bit_cast(int, x)));
}
#define FENCE() __builtin_amdgcn_sched_barrier(0)

__device__ __forceinline__ void rot2(v2f& s, v2f& c, const v2f ts, const v2f td) {
    v2f u = __builtin_elementwise_fma(s, td, s);
    u = __builtin_elementwise_fma(c, ts, u);
    v2f v = __builtin_elementwise_fma(c, td, c);
    v = __builtin_elementwise_fma(-s, ts, v);
    s = u; c = v;
}
__device__ __forceinline__ void rot1(float& s, float& c, const float ts, const float td) {
    float u = __builtin_fmaf(s, td, s); u = __builtin_fmaf(c, ts, u);
    float v = __builtin_fmaf(c, td, c); v = __builtin_fmaf(-s, ts, v);
    s = u; c = v;
}

// ---- ws[0] = sum(omega), deterministic single-block reduce ----
__global__ __launch_bounds__(1024) void sw_kernel(const float* __restrict__ om,
                                                  float* __restrict__ ws) {
    __shared__ float red[16];
    const int tid = threadIdx.x;
    float a = 0.f;
    for (int i = tid; i < V_DIM; i += 1024) a += om[i];
    #pragma unroll
    for (int off = 32; off > 0; off >>= 1) a += __shfl_xor(a, off, 64);
    if ((tid & 63) == 0) red[tid >> 6] = a;
    __syncthreads();
    if (tid == 0) {
        float t = 0.f;
        #pragma unroll
        for (int i = 0; i < 16; ++i) t += red[i];
        ws[0] = t;
    }
}

// ---- tbl4[q] = (sin(.1w[2q]), sin(.1w[2q+1]), cos(.1w[2q])-1, cos(.1w[2q+1])-1) ----
__global__ __launch_bounds__(256) void tbl_kernel(const float* __restrict__ om,
                                                  float4* __restrict__ tbl4) {
    const int q = blockIdx.x * 256 + threadIdx.x;
    if (q < NSTOT * NT) {
        const float t0 = (0.1f * INV2PI) * om[2 * q];
        const float t1 = (0.1f * INV2PI) * om[2 * q + 1];
        tbl4[q] = make_float4(fsin(t0), fsin(t1), fcos(t0) - 1.f, fcos(t1) - 1.f);
    }
}

__global__ __launch_bounds__(NT)
void kuramoto_kernel(const float* __restrict__ lg_,
                     const float* __restrict__ nz_,
                     const float* __restrict__ om_,
                     float* __restrict__ out_,
                     const float4* __restrict__ tbl4,
                     const float* __restrict__ swp) {
    __shared__ uint2 st[NSL][NT];        // 77,824 B : f16 pair state (s01,c01)
    __shared__ float redA[21][8];        // 672 B
    __shared__ float redB[8];            // 32 B

    const int tid = threadIdx.x;
    const size_t base = (size_t)blockIdx.x * V_DIM;
    const float* __restrict__ lg = lg_ + base;
    const float* __restrict__ nz = nz_ + base;
    float* __restrict__ op = out_ + base;

    float vS[NSTEP], vC[NSTEP];
    #pragma unroll
    for (int t = 0; t < NSTEP; ++t) { vS[t] = 0.f; vC[t] = 0.f; }
    float sp0 = 0.f;
    uint2 rst[NSR];
    float tstate_s, tstate_c, tts, ttd;   // tail (tid < TAILN only)

    // ---------------- pass A ----------------
    auto passA = [&](int m) -> uint2 {
        const int e = m * STRIDE + 2 * tid;
        const v2f l = *(const v2f*)(lg + e);
        const v2f n = *(const v2f*)(nz + e);
        const v2f p0 = __builtin_elementwise_fma(v2f{0.1f, 0.1f}, l, n);
        sp0 += p0.x + p0.y;
        const float4 tb = tbl4[m * NT + tid];
        const v2f ts = {tb.x, tb.y}, td = {tb.z, tb.w};
        v2f s = {fsin(p0.x * INV2PI), fsin(p0.y * INV2PI)};
        v2f c = {fcos(p0.x * INV2PI), fcos(p0.y * INV2PI)};
        uint2 hp;
        hp.x = __builtin_bit_cast(unsigned, __floats2half2_rn(s.x, s.y));
        hp.y = __builtin_bit_cast(unsigned, __floats2half2_rn(c.x, c.y));
        #pragma unroll
        for (int t = 0; t < NSTEP; ++t) {
            vS[t] += s.x + s.y; vC[t] += c.x + c.y;
            rot2(s, c, ts, td);
        }
        return hp;
    };
    #pragma unroll
    for (int m = 0; m < NSR; ++m) { rst[m] = passA(m); FENCE(); }
    #pragma unroll 1
    for (int m = NSR; m < NSTOT; ++m) { st[m - NSR][tid] = passA(m); }
    if (tid < TAILN) {   // tail, scalar
        const int e = TAIL_B + tid;
        const float p0 = __builtin_fmaf(0.1f, lg[e], nz[e]);
        sp0 += p0;
        float s = fsin(p0 * INV2PI), c = fcos(p0 * INV2PI);
        tstate_s = s; tstate_c = c;
        const float th = (0.1f * INV2PI) * om_[e];
        tts = fsin(th); ttd = fcos(th) - 1.f;
        #pragma unroll
        for (int t = 0; t < NSTEP; ++t) { vS[t] += s; vC[t] += c; rot1(s, c, tts, ttd); }
    }

    // ---------------- reduce 21 values (barrier #1) ----------------
    #pragma unroll
    for (int off = 32; off > 0; off >>= 1) {
        #pragma unroll
        for (int t = 0; t < NSTEP; ++t) {
            vS[t] += __shfl_xor(vS[t], off, 64);
            vC[t] += __shfl_xor(vC[t], off, 64);
        }
        sp0 += __shfl_xor(sp0, off, 64);
    }
    const int wid = tid >> 6;
    if ((tid & 63) == 0) {
        #pragma unroll
        for (int t = 0; t < NSTEP; ++t) { redA[t][wid] = vS[t]; redA[NSTEP + t][wid] = vC[t]; }
        redA[20][wid] = sp0;
    }
    __syncthreads();
    float dSt[NSTEP], dCt[NSTEP], cM, sM;
    {
        #pragma unroll
        for (int t = 0; t < NSTEP; ++t) {
            float a = 0.f, b = 0.f;
            #pragma unroll
            for (int i = 0; i < NT / 64; ++i) { a += redA[t][i]; b += redA[NSTEP + t][i]; }
            dSt[t] = rfl(DTC * a);
            dCt[t] = rfl(DTC * b);
        }
        float a = 0.f;
        #pragma unroll
        for (int i = 0; i < NT / 64; ++i) a += redA[20][i];
        const float M = (a + swp[0]) / (float)V_DIM;
        cM = rfl(fcos(M * INV2PI)); sM = rfl(fsin(M * INV2PI));
    }

    // ---------------- pass B ----------------
    float es = 0.f;
    auto passB = [&](uint2 hp, int m) -> uint2 {
        const __half2 hs = __builtin_bit_cast(__half2, hp.x);
        const __half2 hc = __builtin_bit_cast(__half2, hp.y);
        v2f s = {__low2float(hs), __high2float(hs)};
        v2f c = {__low2float(hc), __high2float(hc)};
        const float4 tb = tbl4[m * NT + tid];
        const v2f ts = {tb.x, tb.y}, td = {tb.z, tb.w};
        v2f eps = {0.f, 0.f};
        #pragma unroll
        for (int t = 0; t < NSTEP; ++t) {
            eps = __builtin_elementwise_fma(s, v2f{dCt[t], dCt[t]}, eps);
            eps = __builtin_elementwise_fma(-c, v2f{dSt[t], dSt[t]}, eps);
            rot2(s, c, ts, td);
        }
        const v2f s2 = __builtin_elementwise_fma(c, eps, s);      // 1st-order eps-rot
        const v2f c2 = __builtin_elementwise_fma(-s, eps, c);
        v2f coh = __builtin_elementwise_fma(s2, v2f{sM, sM}, v2f{0.f, 0.f});
        coh = __builtin_elementwise_fma(c2, v2f{cM, cM}, coh);
        const v2f ev = {__expf(coh.x), __expf(coh.y)};
        es += ev.x + ev.y;
        return __builtin_bit_cast(uint2, ev);                     // stash f32 pair
    };
    #pragma unroll
    for (int m = 0; m < NSR; ++m) { rst[m] = passB(rst[m], m); FENCE(); }
    #pragma unroll 1
    for (int m = NSR; m < NSTOT; ++m) { st[m - NSR][tid] = passB(st[m - NSR][tid], m); }
    float etail = 0.f;
    if (tid < TAILN) {   // tail
        float s = tstate_s, c = tstate_c;
        float ep = 0.f;
        #pragma unroll
        for (int t = 0; t < NSTEP; ++t) {
            ep = __builtin_fmaf(s, dCt[t], ep);
            ep = __builtin_fmaf(-c, dSt[t], ep);
            rot1(s, c, tts, ttd);
        }
        const float s2 = __builtin_fmaf(c, ep, s);
        const float c2 = __builtin_fmaf(-s, ep, c);
        etail = __expf(__builtin_fmaf(c2, cM, s2 * sM));
        es += etail;
    }

    // ---------------- esum reduce (barrier #2) ----------------
    #pragma unroll
    for (int off = 32; off > 0; off >>= 1) es += __shfl_xor(es, off, 64);
    if ((tid & 63) == 0) redB[wid] = es;
    __syncthreads();
    float tot = 0.f;
    #pragma unroll
    for (int i = 0; i < NT / 64; ++i) tot += redB[i];
    const float inv = 1.f / tot;

    // ---------------- pass C: stores ----------------
    #pragma unroll
    for (int m = 0; m < NSR; ++m) {
        const v2f ev = __builtin_bit_cast(v2f, rst[m]);
        *(v2f*)(op + m * STRIDE + 2 * tid) = ev * inv;
    }
    #pragma unroll 1
    for (int m = NSR; m < NSTOT; ++m) {
        const v2f ev = __builtin_bit_cast(v2f, st[m - NSR][tid]);
        *(v2f*)(op + m * STRIDE + 2 * tid) = ev * inv;
    }
    if (tid < TAILN) op[TAIL_B + tid] = etail * inv;
}

extern "C" void kernel_launch(void* const* d_in, const int* in_sizes, int n_in,
                              void* d_out, int out_size, void* d_ws, size_t ws_size,
                              hipStream_t stream) {
    const float* logits = (const float*)d_in[0];
    const float* omega  = (const float*)d_in[1];  // natural_frequencies [V]
    const float* noise  = (const float*)d_in[2];
    float* out = (float*)d_out;
    float* swp = (float*)d_ws;                          // ws[0] = sum(omega)
    float4* tbl4 = (float4*)((char*)d_ws + 16);         // 401,408 B
    (void)in_sizes; (void)n_in; (void)out_size; (void)ws_size;

    sw_kernel<<<1, 1024, 0, stream>>>(omega, swp);
    tbl_kernel<<<(NSTOT * NT + 255) / 256, 256, 0, stream>>>(omega, tbl4);
    kuramoto_kernel<<<NROWS, NT, 0, stream>>>(logits, noise, omega, out, tbl4, swp);
}

// Round 14
// 277.605 us; speedup vs baseline: 2.7536x; 2.7536x over previous
//
#include <hip/hip_runtime.h>
#include <hip/hip_fp16.h>

// Kuramoto phase dynamics + coherence softmax. B*S=1024 rows, V=50257, 10 steps.
// Two-pass trajectory scheme (validated r11-r13, absmax 2.38e-7 = 1 ulp),
// now (NEARLY) STATELESS to defeat the register allocator (r8/r12/r13: any
// big per-element register state spills; allocator budget = 2 blocks/CU ->
// 64 VGPR @1024t, 84 @768t, 128 @512t):
//   Pass A: stream lg/nz, p0 = nz+0.1*lg, (s,c)=sincos(p0), rotate 10 steps
//           via float4 tbl (sin .1w, cos .1w - 1), accumulate S_t,C_t,Sum(p0).
//           NOTHING stored. 21-value block reduce (barrier #1).
//   Pass B: RELOAD lg/nz, recompute (s,c), replay rotation accumulating
//           eps = sum_t(s_t*dCt - c_t*dSt); 1st-order eps-rotation;
//           coh = c*cM + s*sM; e = exp(coh). e stashed: 38 stripes -> LDS f16
//           half2 (77.8 KB; e in [.37,2.7], rel err 7e-4 -> 2e-8 on out),
//           5 stripes -> 10 VGPRs, 6 stripes -> own final out slots (f32,
//           in-place, race-free), tail -> 1 reg. esum reduce (barrier #2).
//   Pass C: scale everything by inv = 1/esum, coalesced float2 stores.
// Persistent registers: 21 accumulators (A) / 20 SGPR dSt,dCt + 10 stash (B).
// LDS 78.5 KB -> 2 blocks/CU, 16 waves/CU. mean(p_final) = (Sum p0 +
// Sum omega)/V (sum_i eps_i == 0 identically); Sum omega via sw_kernel.

#define V_DIM   50257
#define NROWS   1024
#define NT      512
#define NS_LDS  38                // stripes with e stashed in LDS (f16)
#define NS_REG  5                 // stripes with e stashed in regs (f32)
#define NS_OUT  6                 // stripes with e stashed in out (f32)
#define NSTOT   (NS_LDS + NS_REG + NS_OUT)   // 49 stripes x 1024 elems
#define STRIDE  (2 * NT)          // 1024
#define TAIL_B  (NSTOT * STRIDE)  // 50176
#define TAILN   (V_DIM - TAIL_B)  // 81
#define NSTEP   10
#define INV2PI  0.15915494309189535f
#define DTC     (0.1f * (0.1f / (float)V_DIM))

typedef float v2f __attribute__((ext_vector_type(2)));

__device__ __forceinline__ float fsin(float r) { return __builtin_amdgcn_sinf(r); }
__device__ __forceinline__ float fcos(float r) { return __builtin_amdgcn_cosf(r); }
__device__ __forceinline__ float rfl(float x) {
    return __builtin_bit_cast(float, __builtin_amdgcn_readfirstlane(__builtin_bit_cast(int, x)));
}

__device__ __forceinline__ void rot2(v2f& s, v2f& c, const v2f ts, const v2f td) {
    v2f u = __builtin_elementwise_fma(s, td, s);
    u = __builtin_elementwise_fma(c, ts, u);
    v2f v = __builtin_elementwise_fma(c, td, c);
    v = __builtin_elementwise_fma(-s, ts, v);
    s = u; c = v;
}
__device__ __forceinline__ void rot1(float& s, float& c, const float ts, const float td) {
    float u = __builtin_fmaf(s, td, s); u = __builtin_fmaf(c, ts, u);
    float v = __builtin_fmaf(c, td, c); v = __builtin_fmaf(-s, ts, v);
    s = u; c = v;
}

// ---- ws[0] = sum(omega), deterministic single-block reduce ----
__global__ __launch_bounds__(1024) void sw_kernel(const float* __restrict__ om,
                                                  float* __restrict__ ws) {
    __shared__ float red[16];
    const int tid = threadIdx.x;
    float a = 0.f;
    for (int i = tid; i < V_DIM; i += 1024) a += om[i];
    #pragma unroll
    for (int off = 32; off > 0; off >>= 1) a += __shfl_xor(a, off, 64);
    if ((tid & 63) == 0) red[tid >> 6] = a;
    __syncthreads();
    if (tid == 0) {
        float t = 0.f;
        #pragma unroll
        for (int i = 0; i < 16; ++i) t += red[i];
        ws[0] = t;
    }
}

// ---- tbl4[q] = (sin(.1w[2q]), sin(.1w[2q+1]), cos(.1w[2q])-1, cos(.1w[2q+1])-1) ----
__global__ __launch_bounds__(256) void tbl_kernel(const float* __restrict__ om,
                                                  float4* __restrict__ tbl4) {
    const int q = blockIdx.x * 256 + threadIdx.x;
    if (q < NSTOT * NT) {
        const float t0 = (0.1f * INV2PI) * om[2 * q];
        const float t1 = (0.1f * INV2PI) * om[2 * q + 1];
        tbl4[q] = make_float4(fsin(t0), fsin(t1), fcos(t0) - 1.f, fcos(t1) - 1.f);
    }
}

__global__ __launch_bounds__(NT)
void kuramoto_kernel(const float* __restrict__ lg_,
                     const float* __restrict__ nz_,
                     const float* __restrict__ om_,
                     float* __restrict__ out_,
                     const float4* __restrict__ tbl4,
                     const float* __restrict__ swp) {
    __shared__ unsigned st[NS_LDS][NT];  // 77,824 B : e pair as half2
    __shared__ float redA[21][8];        // 672 B
    __shared__ float redB[8];            // 32 B

    const int tid = threadIdx.x;
    const size_t base = (size_t)blockIdx.x * V_DIM;
    const float* __restrict__ lg = lg_ + base;
    const float* __restrict__ nz = nz_ + base;
    float* __restrict__ op = out_ + base;

    // ---------------- pass A: sums only, no state ----------------
    float vS[NSTEP], vC[NSTEP];
    #pragma unroll
    for (int t = 0; t < NSTEP; ++t) { vS[t] = 0.f; vC[t] = 0.f; }
    float sp0 = 0.f;

    #pragma unroll 1
    for (int m = 0; m < NSTOT; ++m) {
        const int e = m * STRIDE + 2 * tid;
        const v2f l = *(const v2f*)(lg + e);
        const v2f n = *(const v2f*)(nz + e);
        const v2f p0 = __builtin_elementwise_fma(v2f{0.1f, 0.1f}, l, n);
        sp0 += p0.x + p0.y;
        const float4 tb = tbl4[m * NT + tid];
        const v2f ts = {tb.x, tb.y}, td = {tb.z, tb.w};
        v2f s = {fsin(p0.x * INV2PI), fsin(p0.y * INV2PI)};
        v2f c = {fcos(p0.x * INV2PI), fcos(p0.y * INV2PI)};
        #pragma unroll
        for (int t = 0; t < NSTEP; ++t) {
            vS[t] += s.x + s.y; vC[t] += c.x + c.y;
            rot2(s, c, ts, td);
        }
    }
    if (tid < TAILN) {
        const int e = TAIL_B + tid;
        const float p0 = __builtin_fmaf(0.1f, lg[e], nz[e]);
        sp0 += p0;
        float s = fsin(p0 * INV2PI), c = fcos(p0 * INV2PI);
        const float th = (0.1f * INV2PI) * om_[e];
        const float ts = fsin(th), td = fcos(th) - 1.f;
        #pragma unroll
        for (int t = 0; t < NSTEP; ++t) { vS[t] += s; vC[t] += c; rot1(s, c, ts, td); }
    }

    // ---------------- reduce 21 values (barrier #1) ----------------
    #pragma unroll
    for (int off = 32; off > 0; off >>= 1) {
        #pragma unroll
        for (int t = 0; t < NSTEP; ++t) {
            vS[t] += __shfl_xor(vS[t], off, 64);
            vC[t] += __shfl_xor(vC[t], off, 64);
        }
        sp0 += __shfl_xor(sp0, off, 64);
    }
    const int wid = tid >> 6;
    if ((tid & 63) == 0) {
        #pragma unroll
        for (int t = 0; t < NSTEP; ++t) { redA[t][wid] = vS[t]; redA[NSTEP + t][wid] = vC[t]; }
        redA[20][wid] = sp0;
    }
    __syncthreads();
    float dSt[NSTEP], dCt[NSTEP], cM, sM;
    {
        #pragma unroll
        for (int t = 0; t < NSTEP; ++t) {
            float a = 0.f, b = 0.f;
            #pragma unroll
            for (int i = 0; i < NT / 64; ++i) { a += redA[t][i]; b += redA[NSTEP + t][i]; }
            dSt[t] = rfl(DTC * a);
            dCt[t] = rfl(DTC * b);
        }
        float a = 0.f;
        #pragma unroll
        for (int i = 0; i < NT / 64; ++i) a += redA[20][i];
        const float M = (a + swp[0]) / (float)V_DIM;
        cM = rfl(fcos(M * INV2PI)); sM = rfl(fsin(M * INV2PI));
    }

    // ---------------- pass B: reload, replay, e -> stash ----------------
    float es = 0.f;
    auto passB = [&](int m) -> v2f {
        const int e = m * STRIDE + 2 * tid;
        const v2f l = *(const v2f*)(lg + e);
        const v2f n = *(const v2f*)(nz + e);
        const v2f p0 = __builtin_elementwise_fma(v2f{0.1f, 0.1f}, l, n);
        const float4 tb = tbl4[m * NT + tid];
        const v2f ts = {tb.x, tb.y}, td = {tb.z, tb.w};
        v2f s = {fsin(p0.x * INV2PI), fsin(p0.y * INV2PI)};
        v2f c = {fcos(p0.x * INV2PI), fcos(p0.y * INV2PI)};
        v2f eps = {0.f, 0.f};
        #pragma unroll
        for (int t = 0; t < NSTEP; ++t) {
            eps = __builtin_elementwise_fma(s, v2f{dCt[t], dCt[t]}, eps);
            eps = __builtin_elementwise_fma(-c, v2f{dSt[t], dSt[t]}, eps);
            rot2(s, c, ts, td);
        }
        const v2f s2 = __builtin_elementwise_fma(c, eps, s);      // 1st-order eps-rot
        const v2f c2 = __builtin_elementwise_fma(-s, eps, c);
        v2f coh = __builtin_elementwise_fma(s2, v2f{sM, sM}, v2f{0.f, 0.f});
        coh = __builtin_elementwise_fma(c2, v2f{cM, cM}, coh);
        const v2f ev = {__expf(coh.x), __expf(coh.y)};
        es += ev.x + ev.y;
        return ev;
    };
    #pragma unroll 1
    for (int m = 0; m < NS_LDS; ++m) {
        const v2f ev = passB(m);
        st[m][tid] = __builtin_bit_cast(unsigned, __floats2half2_rn(ev.x, ev.y));
    }
    v2f rst[NS_REG];
    #pragma unroll
    for (int m = NS_LDS; m < NS_LDS + NS_REG; ++m) {
        rst[m - NS_LDS] = passB(m);
    }
    #pragma unroll 1
    for (int m = NS_LDS + NS_REG; m < NSTOT; ++m) {
        const v2f ev = passB(m);
        *(v2f*)(op + m * STRIDE + 2 * tid) = ev;    // unscaled stash, own slot
    }
    float etail = 0.f;
    if (tid < TAILN) {
        const int e = TAIL_B + tid;
        const float p0 = __builtin_fmaf(0.1f, lg[e], nz[e]);
        float s = fsin(p0 * INV2PI), c = fcos(p0 * INV2PI);
        const float th = (0.1f * INV2PI) * om_[e];
        const float ts = fsin(th), td = fcos(th) - 1.f;
        float ep = 0.f;
        #pragma unroll
        for (int t = 0; t < NSTEP; ++t) {
            ep = __builtin_fmaf(s, dCt[t], ep);
            ep = __builtin_fmaf(-c, dSt[t], ep);
            rot1(s, c, ts, td);
        }
        const float s2 = __builtin_fmaf(c, ep, s);
        const float c2 = __builtin_fmaf(-s, ep, c);
        etail = __expf(__builtin_fmaf(c2, cM, s2 * sM));
        es += etail;
    }

    // ---------------- esum reduce (barrier #2) ----------------
    #pragma unroll
    for (int off = 32; off > 0; off >>= 1) es += __shfl_xor(es, off, 64);
    if ((tid & 63) == 0) redB[wid] = es;
    __syncthreads();
    float tot = 0.f;
    #pragma unroll
    for (int i = 0; i < NT / 64; ++i) tot += redB[i];
    const float inv = 1.f / tot;

    // ---------------- pass C: scale + store ----------------
    #pragma unroll 1
    for (int m = 0; m < NS_LDS; ++m) {
        const __half2 h = __builtin_bit_cast(__half2, st[m][tid]);
        const v2f ev = {__low2float(h), __high2float(h)};
        *(v2f*)(op + m * STRIDE + 2 * tid) = ev * inv;
    }
    #pragma unroll
    for (int m = NS_LDS; m < NS_LDS + NS_REG; ++m) {
        *(v2f*)(op + m * STRIDE + 2 * tid) = rst[m - NS_LDS] * inv;
    }
    #pragma unroll 1
    for (int m = NS_LDS + NS_REG; m < NSTOT; ++m) {
        float* p = op + m * STRIDE + 2 * tid;
        const v2f ev = *(const v2f*)p;               // own stash, race-free
        *(v2f*)p = ev * inv;
    }
    if (tid < TAILN) op[TAIL_B + tid] = etail * inv;
}

extern "C" void kernel_launch(void* const* d_in, const int* in_sizes, int n_in,
                              void* d_out, int out_size, void* d_ws, size_t ws_size,
                              hipStream_t stream) {
    const float* logits = (const float*)d_in[0];
    const float* omega  = (const float*)d_in[1];  // natural_frequencies [V]
    const float* noise  = (const float*)d_in[2];
    float* out = (float*)d_out;
    float* swp = (float*)d_ws;                          // ws[0] = sum(omega)
    float4* tbl4 = (float4*)((char*)d_ws + 16);         // 401,408 B
    (void)in_sizes; (void)n_in; (void)out_size; (void)ws_size;

    sw_kernel<<<1, 1024, 0, stream>>>(omega, swp);
    tbl_kernel<<<(NSTOT * NT + 255) / 256, 256, 0, stream>>>(omega, tbl4);
    kuramoto_kernel<<<NROWS, NT, 0, stream>>>(logits, noise, omega, out, tbl4, swp);
}